// Round 3
// baseline (253.220 us; speedup 1.0000x reference)
//
#include <hip/hip_runtime.h>
#include <math.h>

#define EPSV 1e-8f

// ws layout (multi-copy path):
//   [0, NCOPY*N*8)   : u64 per (copy, node), packed {z:4 | deg:8 | c4sum:26 | s4sum:26}
//                      unit dir adds (1<<52) | (round((c4+1)*2^17)<<26) | round((s4+1)*2^17)
//                      zero dir adds (1<<60) | (1<<52)
//   then NODE_BLOCKS double2 partials {pair_loss_sum, n_pairs}
// Copy index = physical XCC_ID, so each accumulator address is only ever touched
// by workgroups on ONE XCD -> workgroup-scope (L2-resolved) atomics are safe.
static constexpr int NODE_BLOCKS = 256;
static constexpr int NODE_THREADS = 256;
static constexpr int NCOPY = 8;
static constexpr float QSCALE = 131072.0f;          // 2^17
static constexpr double QINV = 1.0 / 131072.0;

__device__ __forceinline__ unsigned long long pack_edge(float dx, float dy) {
    float n2 = dx * dx + dy * dy;
    if (n2 > EPSV * EPSV) {
        float inv = 1.0f / sqrtf(n2);
        float nx = dx * inv, ny = dy * inv;
        // angle quadrupling: (nx,ny)=(cos,sin) -> cos4, sin4 without trig
        float c2 = nx * nx - ny * ny;
        float s2 = 2.0f * nx * ny;
        float c4 = c2 * c2 - s2 * s2;
        float s4 = 2.0f * c2 * s2;
        c4 = fminf(fmaxf(c4, -1.0f), 1.0f);
        s4 = fminf(fmaxf(s4, -1.0f), 1.0f);
        unsigned int c4f = (unsigned int)__float2int_rn((c4 + 1.0f) * QSCALE);
        unsigned int s4f = (unsigned int)__float2int_rn((s4 + 1.0f) * QSCALE);
        return (1ull << 52) | ((unsigned long long)c4f << 26) | (unsigned long long)s4f;
    }
    // zero-length direction (self-edge): counts toward deg and z only
    return (1ull << 60) | (1ull << 52);
}

template <bool MULTI>
__global__ __launch_bounds__(256) void edge_kernel(
    const float2* __restrict__ pos,
    const int* __restrict__ ei,     // (2, E) row-major: src row then dst row
    unsigned long long* __restrict__ acc,
    int E, int N)
{
    unsigned long long* base = acc;
    if (MULTI) {
        unsigned int xcc;
        asm volatile("s_getreg_b32 %0, hwreg(HW_REG_XCC_ID)" : "=s"(xcc));
        base = acc + (size_t)(xcc & 7) * (size_t)N;
    }
    int tid = blockIdx.x * blockDim.x + threadIdx.x;
    int nthreads = gridDim.x * blockDim.x;
    int nvec = E >> 2;  // E divisible by 4
    const int4* src4 = (const int4*)ei;
    const int4* dst4 = (const int4*)(ei + E);
    for (int v = tid; v < nvec; v += nthreads) {
        int4 sv = src4[v];
        int4 tv = dst4[v];
        int ss[4] = {sv.x, sv.y, sv.z, sv.w};
        int tt[4] = {tv.x, tv.y, tv.z, tv.w};
#pragma unroll
        for (int k = 0; k < 4; ++k) {
            int s = ss[k], t = tt[k];
            float2 ps = pos[s];
            float2 pt = pos[t];
            unsigned long long val = pack_edge(pt.x - ps.x, pt.y - ps.y);
            if (MULTI) {
                // L2-resolved RMW: this address belongs exclusively to this XCD
                __hip_atomic_fetch_add(&base[s], val, __ATOMIC_RELAXED,
                                       __HIP_MEMORY_SCOPE_WORKGROUP);
                __hip_atomic_fetch_add(&base[t], val, __ATOMIC_RELAXED,
                                       __HIP_MEMORY_SCOPE_WORKGROUP);
            } else {
                atomicAdd(&base[s], val);
                atomicAdd(&base[t], val);
            }
        }
    }
}

__global__ __launch_bounds__(NODE_THREADS) void node_kernel(
    const unsigned long long* __restrict__ acc,
    double* __restrict__ partials,   // 2 doubles per block
    int N, int ncopy)
{
    int tid = blockIdx.x * blockDim.x + threadIdx.x;
    int nthreads = gridDim.x * blockDim.x;
    double pls = 0.0, npr = 0.0;
    for (int n = tid; n < N; n += nthreads) {
        unsigned long long a = 0;
        for (int c = 0; c < ncopy; ++c)
            a += acc[(size_t)c * N + n];   // packed fields have headroom for 8-way sum
        double s4sum = (double)(a & 0x3FFFFFFull);
        double c4sum = (double)((a >> 26) & 0x3FFFFFFull);
        double deg = (double)((a >> 52) & 0xFFull);
        double z = (double)(a >> 60);
        double u = deg - z;                  // unit-direction count
        double C = c4sum * QINV - u;         // sum of cos(4*phi)
        double S = s4sum * QINV - u;         // sum of sin(4*phi)
        pls += (u * u - C * C - S * S) * 0.0625;  // 0.5*(S2-S4); S2-S4=(u^2-C^2-S^2)/8
        npr += 0.5 * deg * (deg - 1.0);
    }
    __shared__ double sha[4], shb[4];
    for (int off = 32; off > 0; off >>= 1) {
        pls += __shfl_down(pls, off, 64);
        npr += __shfl_down(npr, off, 64);
    }
    int lane = threadIdx.x & 63;
    int wid = threadIdx.x >> 6;
    if (lane == 0) { sha[wid] = pls; shb[wid] = npr; }
    __syncthreads();
    if (threadIdx.x == 0) {
        partials[2 * blockIdx.x + 0] = sha[0] + sha[1] + sha[2] + sha[3];
        partials[2 * blockIdx.x + 1] = shb[0] + shb[1] + shb[2] + shb[3];
    }
}

__global__ __launch_bounds__(256) void final_kernel(
    const double* __restrict__ partials,
    float* __restrict__ out,
    int nb)
{
    double pls = 0.0, npr = 0.0;
    for (int i = threadIdx.x; i < nb; i += blockDim.x) {
        pls += partials[2 * i + 0];
        npr += partials[2 * i + 1];
    }
    __shared__ double sha[4], shb[4];
    for (int off = 32; off > 0; off >>= 1) {
        pls += __shfl_down(pls, off, 64);
        npr += __shfl_down(npr, off, 64);
    }
    int lane = threadIdx.x & 63;
    int wid = threadIdx.x >> 6;
    if (lane == 0) { sha[wid] = pls; shb[wid] = npr; }
    __syncthreads();
    if (threadIdx.x == 0) {
        double a = sha[0] + sha[1] + sha[2] + sha[3];
        double b = shb[0] + shb[1] + shb[2] + shb[3];
        out[0] = (float)(a / fmax(b, 1.0));
    }
}

extern "C" void kernel_launch(void* const* d_in, const int* in_sizes, int n_in,
                              void* d_out, int out_size, void* d_ws, size_t ws_size,
                              hipStream_t stream) {
    const float* pos = (const float*)d_in[0];       // (1, N, 2) -> interleaved x,y
    const int* ei = (const int*)d_in[2];            // (2, E)
    int N = in_sizes[0] / 2;
    int E = in_sizes[2] / 2;
    float* out = (float*)d_out;

    size_t multi_bytes = (size_t)NCOPY * N * 8 + (size_t)NODE_BLOCKS * 16;
    bool multi = ws_size >= multi_bytes;
    int ncopy = multi ? NCOPY : 1;

    unsigned long long* acc = (unsigned long long*)d_ws;
    double* partials = (double*)((char*)d_ws + (size_t)ncopy * N * 8);
    size_t zero_bytes = (size_t)ncopy * N * 8 + (size_t)NODE_BLOCKS * 16;
    hipMemsetAsync(d_ws, 0, zero_bytes, stream);

    int nvec = E >> 2;
    int eb = (nvec + 255) / 256;
    if (multi)
        edge_kernel<true><<<eb, 256, 0, stream>>>((const float2*)pos, ei, acc, E, N);
    else
        edge_kernel<false><<<eb, 256, 0, stream>>>((const float2*)pos, ei, acc, E, N);
    node_kernel<<<NODE_BLOCKS, NODE_THREADS, 0, stream>>>(acc, partials, N, ncopy);
    final_kernel<<<1, 256, 0, stream>>>(partials, out, NODE_BLOCKS);
}

// Round 4
// 195.932 us; speedup vs baseline: 1.2924x; 1.2924x over previous
//
#include <hip/hip_runtime.h>
#include <math.h>

#define EPSV 1e-8f

// ---------------- packed per-endpoint record -------------------------------
// u64 accumulator per node: {z:4 @60 | deg:8 @52 | c4sum:26 @26 | s4sum:26 @0}
// unit dir adds   (1<<52) | (round((c4+1)*2^17)<<26) | round((s4+1)*2^17)
// zero dir adds   (1<<60) | (1<<52)
// decode: u = deg-z; C = c4sum/2^17 - u; S = s4sum/2^17 - u
// per-node: 0.5*(S2-S4) = (u^2 - C^2 - S^2)/16 ; n_pairs += deg*(deg-1)/2
static constexpr float QSCALE = 131072.0f;   // 2^17
static constexpr double QINV = 1.0 / 131072.0;

static constexpr int BLOG = 7;               // 128 nodes per bucket
static constexpr int NPB = 1 << BLOG;
static constexpr int NREP = 4;               // LDS accumulator replication
static constexpr int BIN_BLOCKS = 256;
static constexpr int NODE_BLOCKS = 256;      // fallback path

__device__ __forceinline__ unsigned long long pack_edge(float dx, float dy) {
    float n2 = dx * dx + dy * dy;
    if (n2 > EPSV * EPSV) {
        float inv = 1.0f / sqrtf(n2);
        float nx = dx * inv, ny = dy * inv;
        // angle quadrupling: (nx,ny)=(cos,sin) -> cos4, sin4 without trig
        float c2 = nx * nx - ny * ny;
        float s2 = 2.0f * nx * ny;
        float c4 = c2 * c2 - s2 * s2;
        float s4 = 2.0f * c2 * s2;
        c4 = fminf(fmaxf(c4, -1.0f), 1.0f);
        s4 = fminf(fmaxf(s4, -1.0f), 1.0f);
        unsigned int c4f = (unsigned int)__float2int_rn((c4 + 1.0f) * QSCALE);
        unsigned int s4f = (unsigned int)__float2int_rn((s4 + 1.0f) * QSCALE);
        return (1ull << 52) | ((unsigned long long)c4f << 26) | (unsigned long long)s4f;
    }
    return (1ull << 60) | (1ull << 52);   // zero-length dir (self-edge)
}

__device__ __forceinline__ void decode_accum(unsigned long long a, double& pls, double& npr) {
    double s4sum = (double)(a & 0x3FFFFFFull);
    double c4sum = (double)((a >> 26) & 0x3FFFFFFull);
    double deg = (double)((a >> 52) & 0xFFull);
    double z = (double)(a >> 60);
    double u = deg - z;
    double C = c4sum * QINV - u;
    double S = s4sum * QINV - u;
    pls += (u * u - C * C - S * S) * 0.0625;
    npr += 0.5 * deg * (deg - 1.0);
}

// ---------------- phase 1: bin endpoints by node bucket --------------------
__global__ __launch_bounds__(256) void bin_kernel(
    const int* __restrict__ ei,        // (2,E): src row then dst row
    int E, int NB, int cap,
    unsigned int* __restrict__ gcount, // NB totals (pre-zeroed)
    unsigned int* __restrict__ buf)    // NB*cap endpoint ids
{
    extern __shared__ unsigned int lds[];  // NB: hist, then absolute cursors
    int chunk = (E + gridDim.x - 1) / gridDim.x;
    int e0 = blockIdx.x * chunk;
    int e1 = min(E, e0 + chunk);
    const int* src = ei;
    const int* dst = ei + E;

    for (int i = threadIdx.x; i < NB; i += blockDim.x) lds[i] = 0;
    __syncthreads();
    for (int e = e0 + (int)threadIdx.x; e < e1; e += blockDim.x) {
        int s = src[e], t = dst[e];
        atomicAdd(&lds[s >> BLOG], 1u);
        atomicAdd(&lds[t >> BLOG], 1u);
    }
    __syncthreads();
    // reserve a contiguous sub-range per (block,bucket); convert to absolute cursor
    for (int i = threadIdx.x; i < NB; i += blockDim.x) {
        unsigned int c = lds[i];
        unsigned int base = c ? atomicAdd(&gcount[i], c) : 0u;
        lds[i] = (unsigned int)i * (unsigned int)cap + base;
    }
    __syncthreads();
    for (int e = e0 + (int)threadIdx.x; e < e1; e += blockDim.x) {
        int s = src[e], t = dst[e];
        unsigned int bs = (unsigned int)(s >> BLOG);
        unsigned int bt = (unsigned int)(t >> BLOG);
        unsigned int ps = atomicAdd(&lds[bs], 1u);
        if (ps < (bs + 1u) * (unsigned int)cap)   // overflow guard (stat. impossible)
            buf[ps] = ((unsigned int)e << 1);
        unsigned int pt = atomicAdd(&lds[bt], 1u);
        if (pt < (bt + 1u) * (unsigned int)cap)
            buf[pt] = ((unsigned int)e << 1) | 1u;
    }
}

// ---------------- phase 2: per-bucket LDS reduction ------------------------
__global__ __launch_bounds__(256) void bucket_kernel(
    const float2* __restrict__ pos,
    const int* __restrict__ ei, int E, int cap,
    const unsigned int* __restrict__ gcount,
    const unsigned int* __restrict__ buf,
    double* __restrict__ partials)     // 2 doubles per bucket
{
    __shared__ unsigned long long acc[NREP][NPB];
    __shared__ double sha[4], shb[4];
    int b = blockIdx.x;
    int cnt = min((int)gcount[b], cap);
    for (int i = threadIdx.x; i < NREP * NPB; i += blockDim.x)
        ((unsigned long long*)acc)[i] = 0ull;
    __syncthreads();

    const unsigned int* bb = buf + (size_t)b * (size_t)cap;
    const int* src = ei;
    const int* dst = ei + E;
    int rep = threadIdx.x & (NREP - 1);
    for (int i = threadIdx.x; i < cnt; i += blockDim.x) {
        unsigned int p = bb[i];
        int e = (int)(p >> 1);
        int a = src[e], c = dst[e];
        int own = (p & 1u) ? c : a;
        // direction sign is irrelevant under angle-quadrupling (4*phi)
        float2 pa = pos[a], pc = pos[c];
        unsigned long long val = pack_edge(pc.x - pa.x, pc.y - pa.y);
        atomicAdd(&acc[rep][own & (NPB - 1)], val);
    }
    __syncthreads();

    double pls = 0.0, npr = 0.0;
    for (int i = threadIdx.x; i < NPB; i += blockDim.x) {
        unsigned long long a = acc[0][i];
        for (int r = 1; r < NREP; ++r) a += acc[r][i];
        decode_accum(a, pls, npr);
    }
    for (int off = 32; off > 0; off >>= 1) {
        pls += __shfl_down(pls, off, 64);
        npr += __shfl_down(npr, off, 64);
    }
    int lane = threadIdx.x & 63;
    int wid = threadIdx.x >> 6;
    if (lane == 0) { sha[wid] = pls; shb[wid] = npr; }
    __syncthreads();
    if (threadIdx.x == 0) {
        partials[2 * b + 0] = sha[0] + sha[1] + sha[2] + sha[3];
        partials[2 * b + 1] = shb[0] + shb[1] + shb[2] + shb[3];
    }
}

// ---------------- final: sum partials, divide ------------------------------
__global__ __launch_bounds__(256) void final_kernel(
    const double* __restrict__ partials,
    float* __restrict__ out,
    int nb)
{
    double pls = 0.0, npr = 0.0;
    for (int i = threadIdx.x; i < nb; i += blockDim.x) {
        pls += partials[2 * i + 0];
        npr += partials[2 * i + 1];
    }
    __shared__ double sha[4], shb[4];
    for (int off = 32; off > 0; off >>= 1) {
        pls += __shfl_down(pls, off, 64);
        npr += __shfl_down(npr, off, 64);
    }
    int lane = threadIdx.x & 63;
    int wid = threadIdx.x >> 6;
    if (lane == 0) { sha[wid] = pls; shb[wid] = npr; }
    __syncthreads();
    if (threadIdx.x == 0) {
        double a = sha[0] + sha[1] + sha[2] + sha[3];
        double b = shb[0] + shb[1] + shb[2] + shb[3];
        out[0] = (float)(a / fmax(b, 1.0));
    }
}

// ---------------- fallback path (round-2 proven): device atomics -----------
__global__ __launch_bounds__(256) void edge_kernel_fb(
    const float2* __restrict__ pos,
    const int* __restrict__ ei,
    unsigned long long* __restrict__ acc,
    int E)
{
    int tid = blockIdx.x * blockDim.x + threadIdx.x;
    int nthreads = gridDim.x * blockDim.x;
    const int* src = ei;
    const int* dst = ei + E;
    for (int e = tid; e < E; e += nthreads) {
        int s = src[e], t = dst[e];
        float2 ps = pos[s], pt = pos[t];
        unsigned long long val = pack_edge(pt.x - ps.x, pt.y - ps.y);
        atomicAdd(&acc[s], val);
        atomicAdd(&acc[t], val);
    }
}

__global__ __launch_bounds__(256) void node_kernel_fb(
    const unsigned long long* __restrict__ acc,
    double* __restrict__ partials,
    int N)
{
    int tid = blockIdx.x * blockDim.x + threadIdx.x;
    int nthreads = gridDim.x * blockDim.x;
    double pls = 0.0, npr = 0.0;
    for (int n = tid; n < N; n += nthreads)
        decode_accum(acc[n], pls, npr);
    __shared__ double sha[4], shb[4];
    for (int off = 32; off > 0; off >>= 1) {
        pls += __shfl_down(pls, off, 64);
        npr += __shfl_down(npr, off, 64);
    }
    int lane = threadIdx.x & 63;
    int wid = threadIdx.x >> 6;
    if (lane == 0) { sha[wid] = pls; shb[wid] = npr; }
    __syncthreads();
    if (threadIdx.x == 0) {
        partials[2 * blockIdx.x + 0] = sha[0] + sha[1] + sha[2] + sha[3];
        partials[2 * blockIdx.x + 1] = shb[0] + shb[1] + shb[2] + shb[3];
    }
}

extern "C" void kernel_launch(void* const* d_in, const int* in_sizes, int n_in,
                              void* d_out, int out_size, void* d_ws, size_t ws_size,
                              hipStream_t stream) {
    const float* pos = (const float*)d_in[0];   // (1,N,2) interleaved x,y
    const int* ei = (const int*)d_in[2];        // (2,E)
    int N = in_sizes[0] / 2;
    int E = in_sizes[2] / 2;
    float* out = (float*)d_out;

    int NB = (N + NPB - 1) >> BLOG;
    // per-bucket capacity: mean + 16 sigma (binomial), rounded up
    double mean = 2.0 * (double)E * (double)NPB / (double)N;
    double slack = 16.0 * sqrt(mean) + 64.0;
    int cap = (int)(mean + slack);
    cap = (cap + 63) & ~63;

    // ws layout: [partials NB*16][gcount NB*4][buf NB*cap*4]
    size_t off_gc = (size_t)NB * 16;
    size_t off_buf = off_gc + (size_t)NB * 4;
    size_t need = off_buf + (size_t)NB * (size_t)cap * 4;

    if (ws_size >= need && NB <= 65536) {
        double* partials = (double*)d_ws;
        unsigned int* gcount = (unsigned int*)((char*)d_ws + off_gc);
        unsigned int* buf = (unsigned int*)((char*)d_ws + off_buf);

        hipMemsetAsync(gcount, 0, (size_t)NB * 4, stream);
        bin_kernel<<<BIN_BLOCKS, 256, (size_t)NB * 4, stream>>>(
            ei, E, NB, cap, gcount, buf);
        bucket_kernel<<<NB, 256, 0, stream>>>(
            (const float2*)pos, ei, E, cap, gcount, buf, partials);
        final_kernel<<<1, 256, 0, stream>>>(partials, out, NB);
    } else {
        // fallback: device-atomic accumulation (round-2 proven path)
        unsigned long long* acc = (unsigned long long*)d_ws;
        double* partials = (double*)((char*)d_ws + (size_t)N * 8);
        hipMemsetAsync(d_ws, 0, (size_t)N * 8 + (size_t)NODE_BLOCKS * 16, stream);
        int eb = min((E + 255) / 256, 2048);
        edge_kernel_fb<<<eb, 256, 0, stream>>>((const float2*)pos, ei, acc, E);
        node_kernel_fb<<<NODE_BLOCKS, 256, 0, stream>>>(acc, partials, N);
        final_kernel<<<1, 256, 0, stream>>>(partials, out, NODE_BLOCKS);
    }
}

// Round 5
// 137.951 us; speedup vs baseline: 1.8356x; 1.4203x over previous
//
#include <hip/hip_runtime.h>
#include <math.h>

#define EPSV 1e-8f

// ---------------- math ------------------------------------------------------
// Per node n with unit incident dirs d_i = (cos phi_i, sin phi_i):
//   0.5*(S2-S4) = (u^2 - C^2 - S^2)/16,  C = sum cos(4 phi_i), S = sum sin(4 phi_i)
//   u = #unit dirs (deg minus zero-length self-edge dirs)
// Record (u32): [31] z | [30:24] local node id | [23:12] c4q | [11:0] s4q
//   unit dir:  c4q = round((c4+1)*1024) in [0,2048], same for s4q
//   zero dir:  z=1, c4q = s4q = 1024 (encodes c4=s4=0 with the same +1 bias)
// Accumulator (u64): {z:4 @60 | deg:8 @52 | c4sum:26 @26 | s4sum:26 @0}
//   decode: C = c4sum/1024 - deg ; S = s4sum/1024 - deg ; u = deg - z
static constexpr double QINV = 1.0 / 1024.0;

static constexpr int BLOG = 7;               // 128 nodes per bucket
static constexpr int NPB = 1 << BLOG;
static constexpr int NREP = 4;               // LDS accumulator replication
static constexpr int BIN_BLOCKS = 256;
static constexpr int NODE_BLOCKS = 256;      // fallback path

__device__ __forceinline__ unsigned int make_record(float dx, float dy) {
    float n2 = dx * dx + dy * dy;
    if (n2 > EPSV * EPSV) {
        float inv = 1.0f / n2;
        // double angle twice without sqrt: c2=cos2phi, s2=sin2phi from (dx,dy)
        float c2 = (dx * dx - dy * dy) * inv;
        float s2 = (2.0f * dx * dy) * inv;
        float c4 = c2 * c2 - s2 * s2;
        float s4 = 2.0f * c2 * s2;
        c4 = fminf(fmaxf(c4, -1.0f), 1.0f);
        s4 = fminf(fmaxf(s4, -1.0f), 1.0f);
        unsigned int c4q = (unsigned int)__float2int_rn((c4 + 1.0f) * 1024.0f);
        unsigned int s4q = (unsigned int)__float2int_rn((s4 + 1.0f) * 1024.0f);
        return (c4q << 12) | s4q;
    }
    return (1u << 31) | (1024u << 12) | 1024u;   // zero-length dir (self-edge)
}

__device__ __forceinline__ void decode_accum(unsigned long long a, double& pls, double& npr) {
    double s4sum = (double)(a & 0x3FFFFFFull);
    double c4sum = (double)((a >> 26) & 0x3FFFFFFull);
    double deg = (double)((a >> 52) & 0xFFull);
    double z = (double)(a >> 60);
    double u = deg - z;
    double C = c4sum * QINV - deg;
    double S = s4sum * QINV - deg;
    pls += (u * u - C * C - S * S) * 0.0625;
    npr += 0.5 * deg * (deg - 1.0);
}

// ---------------- phase 1: bin self-contained records by node bucket --------
__global__ __launch_bounds__(256) void bin_kernel(
    const float2* __restrict__ pos,
    const int* __restrict__ ei,        // (2,E): src row then dst row
    int E, int NB, int cap,
    unsigned int* __restrict__ gcount, // NB totals (pre-zeroed)
    unsigned int* __restrict__ buf)    // NB*cap records
{
    extern __shared__ unsigned int lds[];  // NB: hist, then absolute cursors
    int chunk = (E + gridDim.x - 1) / gridDim.x;
    int e0 = blockIdx.x * chunk;
    int e1 = min(E, e0 + chunk);
    const int* src = ei;
    const int* dst = ei + E;

    for (int i = threadIdx.x; i < NB; i += blockDim.x) lds[i] = 0;
    __syncthreads();
    for (int e = e0 + (int)threadIdx.x; e < e1; e += blockDim.x) {
        int s = src[e], t = dst[e];
        atomicAdd(&lds[s >> BLOG], 1u);
        atomicAdd(&lds[t >> BLOG], 1u);
    }
    __syncthreads();
    // reserve a contiguous sub-range per (block,bucket); convert to absolute cursor
    for (int i = threadIdx.x; i < NB; i += blockDim.x) {
        unsigned int c = lds[i];
        unsigned int base = c ? atomicAdd(&gcount[i], c) : 0u;
        lds[i] = (unsigned int)i * (unsigned int)cap + base;
    }
    __syncthreads();
    for (int e = e0 + (int)threadIdx.x; e < e1; e += blockDim.x) {
        int s = src[e], t = dst[e];
        float2 ps = pos[s], pt = pos[t];
        unsigned int rec = make_record(pt.x - ps.x, pt.y - ps.y);
        unsigned int bs = (unsigned int)(s >> BLOG);
        unsigned int bt = (unsigned int)(t >> BLOG);
        unsigned int is = atomicAdd(&lds[bs], 1u);
        if (is < (bs + 1u) * (unsigned int)cap)   // overflow guard (stat. impossible)
            buf[is] = rec | ((unsigned int)(s & (NPB - 1)) << 24);
        unsigned int it = atomicAdd(&lds[bt], 1u);
        if (it < (bt + 1u) * (unsigned int)cap)
            buf[it] = rec | ((unsigned int)(t & (NPB - 1)) << 24);
    }
}

// ---------------- phase 2: per-bucket streaming LDS reduction ---------------
__global__ __launch_bounds__(256) void bucket_kernel(
    const unsigned int* __restrict__ gcount,
    const unsigned int* __restrict__ buf,
    int cap,
    double* __restrict__ partials)     // 2 doubles per bucket
{
    __shared__ unsigned long long acc[NREP][NPB];
    __shared__ double sha[4], shb[4];
    int b = blockIdx.x;
    int cnt = min((int)gcount[b], cap);
    for (int i = threadIdx.x; i < NREP * NPB; i += blockDim.x)
        ((unsigned long long*)acc)[i] = 0ull;
    __syncthreads();

    const unsigned int* bb = buf + (size_t)b * (size_t)cap;
    int rep = threadIdx.x & (NREP - 1);
    for (int i = threadIdx.x; i < cnt; i += blockDim.x) {
        unsigned int r = bb[i];
        unsigned long long z = (unsigned long long)(r >> 31);
        unsigned int id = (r >> 24) & (NPB - 1);
        unsigned long long c4q = (r >> 12) & 0xFFFu;
        unsigned long long s4q = r & 0xFFFu;
        unsigned long long val = (z << 60) | (1ull << 52) | (c4q << 26) | s4q;
        atomicAdd(&acc[rep][id], val);
    }
    __syncthreads();

    double pls = 0.0, npr = 0.0;
    for (int i = threadIdx.x; i < NPB; i += blockDim.x) {
        unsigned long long a = acc[0][i];
        for (int r = 1; r < NREP; ++r) a += acc[r][i];
        decode_accum(a, pls, npr);
    }
    for (int off = 32; off > 0; off >>= 1) {
        pls += __shfl_down(pls, off, 64);
        npr += __shfl_down(npr, off, 64);
    }
    int lane = threadIdx.x & 63;
    int wid = threadIdx.x >> 6;
    if (lane == 0) { sha[wid] = pls; shb[wid] = npr; }
    __syncthreads();
    if (threadIdx.x == 0) {
        partials[2 * b + 0] = sha[0] + sha[1] + sha[2] + sha[3];
        partials[2 * b + 1] = shb[0] + shb[1] + shb[2] + shb[3];
    }
}

// ---------------- final: sum partials, divide ------------------------------
__global__ __launch_bounds__(256) void final_kernel(
    const double* __restrict__ partials,
    float* __restrict__ out,
    int nb)
{
    double pls = 0.0, npr = 0.0;
    for (int i = threadIdx.x; i < nb; i += blockDim.x) {
        pls += partials[2 * i + 0];
        npr += partials[2 * i + 1];
    }
    __shared__ double sha[4], shb[4];
    for (int off = 32; off > 0; off >>= 1) {
        pls += __shfl_down(pls, off, 64);
        npr += __shfl_down(npr, off, 64);
    }
    int lane = threadIdx.x & 63;
    int wid = threadIdx.x >> 6;
    if (lane == 0) { sha[wid] = pls; shb[wid] = npr; }
    __syncthreads();
    if (threadIdx.x == 0) {
        double a = sha[0] + sha[1] + sha[2] + sha[3];
        double b = shb[0] + shb[1] + shb[2] + shb[3];
        out[0] = (float)(a / fmax(b, 1.0));
    }
}

// ---------------- fallback path (round-2 proven): device atomics -----------
// u64 acc layout here: deg at 52, z at 60, c4sum/s4sum at 2^10 scale as above.
__global__ __launch_bounds__(256) void edge_kernel_fb(
    const float2* __restrict__ pos,
    const int* __restrict__ ei,
    unsigned long long* __restrict__ acc,
    int E)
{
    int tid = blockIdx.x * blockDim.x + threadIdx.x;
    int nthreads = gridDim.x * blockDim.x;
    const int* src = ei;
    const int* dst = ei + E;
    for (int e = tid; e < E; e += nthreads) {
        int s = src[e], t = dst[e];
        float2 ps = pos[s], pt = pos[t];
        unsigned int r = make_record(pt.x - ps.x, pt.y - ps.y);
        unsigned long long val = (((unsigned long long)(r >> 31)) << 60) | (1ull << 52)
                               | (((unsigned long long)((r >> 12) & 0xFFFu)) << 26)
                               | (unsigned long long)(r & 0xFFFu);
        atomicAdd(&acc[s], val);
        atomicAdd(&acc[t], val);
    }
}

__global__ __launch_bounds__(256) void node_kernel_fb(
    const unsigned long long* __restrict__ acc,
    double* __restrict__ partials,
    int N)
{
    int tid = blockIdx.x * blockDim.x + threadIdx.x;
    int nthreads = gridDim.x * blockDim.x;
    double pls = 0.0, npr = 0.0;
    for (int n = tid; n < N; n += nthreads)
        decode_accum(acc[n], pls, npr);
    __shared__ double sha[4], shb[4];
    for (int off = 32; off > 0; off >>= 1) {
        pls += __shfl_down(pls, off, 64);
        npr += __shfl_down(npr, off, 64);
    }
    int lane = threadIdx.x & 63;
    int wid = threadIdx.x >> 6;
    if (lane == 0) { sha[wid] = pls; shb[wid] = npr; }
    __syncthreads();
    if (threadIdx.x == 0) {
        partials[2 * blockIdx.x + 0] = sha[0] + sha[1] + sha[2] + sha[3];
        partials[2 * blockIdx.x + 1] = shb[0] + shb[1] + shb[2] + shb[3];
    }
}

extern "C" void kernel_launch(void* const* d_in, const int* in_sizes, int n_in,
                              void* d_out, int out_size, void* d_ws, size_t ws_size,
                              hipStream_t stream) {
    const float* pos = (const float*)d_in[0];   // (1,N,2) interleaved x,y
    const int* ei = (const int*)d_in[2];        // (2,E)
    int N = in_sizes[0] / 2;
    int E = in_sizes[2] / 2;
    float* out = (float*)d_out;

    int NB = (N + NPB - 1) >> BLOG;
    // per-bucket capacity: mean + 16 sigma (binomial), rounded up
    double mean = 2.0 * (double)E * (double)NPB / (double)N;
    double slack = 16.0 * sqrt(mean) + 64.0;
    int cap = (int)(mean + slack);
    cap = (cap + 63) & ~63;

    // ws layout: [partials NB*16][gcount NB*4][buf NB*cap*4]
    size_t off_gc = (size_t)NB * 16;
    size_t off_buf = off_gc + (size_t)NB * 4;
    size_t need = off_buf + (size_t)NB * (size_t)cap * 4;

    if (ws_size >= need && NB <= 65536) {
        double* partials = (double*)d_ws;
        unsigned int* gcount = (unsigned int*)((char*)d_ws + off_gc);
        unsigned int* buf = (unsigned int*)((char*)d_ws + off_buf);

        hipMemsetAsync(gcount, 0, (size_t)NB * 4, stream);
        bin_kernel<<<BIN_BLOCKS, 256, (size_t)NB * 4, stream>>>(
            (const float2*)pos, ei, E, NB, cap, gcount, buf);
        bucket_kernel<<<NB, 256, 0, stream>>>(gcount, buf, cap, partials);
        final_kernel<<<1, 256, 0, stream>>>(partials, out, NB);
    } else {
        // fallback: device-atomic accumulation (round-2 proven path)
        unsigned long long* acc = (unsigned long long*)d_ws;
        double* partials = (double*)((char*)d_ws + (size_t)N * 8);
        hipMemsetAsync(d_ws, 0, (size_t)N * 8 + (size_t)NODE_BLOCKS * 16, stream);
        int eb = min((E + 255) / 256, 2048);
        edge_kernel_fb<<<eb, 256, 0, stream>>>((const float2*)pos, ei, acc, E);
        node_kernel_fb<<<NODE_BLOCKS, 256, 0, stream>>>(acc, partials, N);
        final_kernel<<<1, 256, 0, stream>>>(partials, out, NODE_BLOCKS);
    }
}

// Round 6
// 114.665 us; speedup vs baseline: 2.2083x; 1.2031x over previous
//
#include <hip/hip_runtime.h>
#include <math.h>

#define EPSV 1e-8f

// ---------------- math ------------------------------------------------------
// Per node n with unit incident dirs d_i = (cos phi_i, sin phi_i):
//   0.5*(S2-S4) = (u^2 - C^2 - S^2)/16,  C = sum cos(4 phi_i), S = sum sin(4 phi_i)
//   u = deg - z (z = zero-length self-edge dirs, which contribute nothing)
// Record (u32): [31] z | [30:23] local node id (8b) | [22:11] c4q | [10:0] s4q
//   unit dir:  c4q = round((c4+1)*1024) in [0,2048]; s4q = round((s4+1)*512) in [0,1024]
//   zero dir:  z=1, c4q=1024, s4q=512 (same +1 bias, encodes c4=s4=0)
// Accumulator (u64): {z:4 @60 | deg:8 @52 | c4sum:26 @26 | s4sum:26 @0}
//   decode: C = c4sum/1024 - deg ; S = s4sum/512 - deg ; u = deg - z
static constexpr double QC = 1.0 / 1024.0;
static constexpr double QS = 1.0 / 512.0;

static constexpr int BLOG = 8;               // 256 nodes per bucket
static constexpr int NPB = 1 << BLOG;
static constexpr int NBIN = 512;             // bin blocks (each sorts its own chunk)
static constexpr int SRTN = 8192;            // LDS sort capacity (records)
static constexpr int NODE_BLOCKS = 256;      // fallback path

__device__ __forceinline__ unsigned int make_record(float dx, float dy) {
    float n2 = dx * dx + dy * dy;
    if (n2 > EPSV * EPSV) {
        float inv = 1.0f / n2;
        // double angle twice without sqrt: c2=cos2phi, s2=sin2phi from (dx,dy)
        float c2 = (dx * dx - dy * dy) * inv;
        float s2 = (2.0f * dx * dy) * inv;
        float c4 = c2 * c2 - s2 * s2;
        float s4 = 2.0f * c2 * s2;
        c4 = fminf(fmaxf(c4, -1.0f), 1.0f);
        s4 = fminf(fmaxf(s4, -1.0f), 1.0f);
        unsigned int c4q = (unsigned int)__float2int_rn((c4 + 1.0f) * 1024.0f);
        unsigned int s4q = (unsigned int)__float2int_rn((s4 + 1.0f) * 512.0f);
        return (c4q << 11) | s4q;
    }
    return (1u << 31) | (1024u << 11) | 512u;   // zero-length dir (self-edge)
}

__device__ __forceinline__ unsigned long long rec_to_val(unsigned int r) {
    return (((unsigned long long)(r >> 31)) << 60) | (1ull << 52)
         | (((unsigned long long)((r >> 11) & 0xFFFu)) << 26)
         | (unsigned long long)(r & 0x7FFu);
}

__device__ __forceinline__ void decode_accum(unsigned long long a, double& pls, double& npr) {
    double s4sum = (double)(a & 0x3FFFFFFull);
    double c4sum = (double)((a >> 26) & 0x3FFFFFFull);
    double deg = (double)((a >> 52) & 0xFFull);
    double z = (double)(a >> 60);
    double u = deg - z;
    double C = c4sum * QC - deg;
    double S = s4sum * QS - deg;
    pls += (u * u - C * C - S * S) * 0.0625;
    npr += 0.5 * deg * (deg - 1.0);
}

// ---------------- phase 1: per-block counting sort of records ---------------
__global__ __launch_bounds__(256) void bin_kernel(
    const float2* __restrict__ pos,
    const int* __restrict__ ei,        // (2,E): src row then dst row
    int E, int NB, int chunk, int rstride,
    unsigned short* __restrict__ ofs_out,  // [NBIN][NB+1] exclusive offsets
    unsigned int* __restrict__ buf)        // [NBIN][rstride] sorted records
{
    __shared__ unsigned int srt[SRTN];
    __shared__ unsigned int hist[512];   // counts, then cursors
    __shared__ unsigned int scan[512];
    int blk = blockIdx.x;
    int t = threadIdx.x;
    int e0 = blk * chunk;
    int e1 = min(E, e0 + chunk);
    int cl = max(0, e1 - e0);
    const int* src = ei;
    const int* dst = ei + E;

    hist[t] = 0; hist[t + 256] = 0;
    __syncthreads();
    for (int e = e0 + t; e < e1; e += 256) {
        atomicAdd(&hist[src[e] >> BLOG], 1u);
        atomicAdd(&hist[dst[e] >> BLOG], 1u);
    }
    __syncthreads();
    // inclusive Hillis-Steele scan over 512 slots
    scan[t] = hist[t]; scan[t + 256] = hist[t + 256];
    __syncthreads();
    for (int d = 1; d < 512; d <<= 1) {
        unsigned a0 = scan[t] + ((t >= d) ? scan[t - d] : 0u);
        int t2 = t + 256;
        unsigned a1 = scan[t2] + ((t2 >= d) ? scan[t2 - d] : 0u);
        __syncthreads();
        scan[t] = a0; scan[t2] = a1;
        __syncthreads();
    }
    // exclusive offsets; emit row; convert hist -> cursors
    unsigned ex0 = scan[t] - hist[t];
    unsigned ex1 = scan[t + 256] - hist[t + 256];
    size_t row = (size_t)blk * (size_t)(NB + 1);
    if (t < NB) ofs_out[row + t] = (unsigned short)ex0;
    if (t + 256 < NB) ofs_out[row + t + 256] = (unsigned short)ex1;
    if (t == 0) ofs_out[row + NB] = (unsigned short)(2 * cl);
    __syncthreads();
    hist[t] = ex0; hist[t + 256] = ex1;
    __syncthreads();
    // place records into LDS sorted array
    for (int e = e0 + t; e < e1; e += 256) {
        int s = src[e], d = dst[e];
        float2 ps = pos[s], pd = pos[d];
        unsigned int rec = make_record(pd.x - ps.x, pd.y - ps.y);
        unsigned is = atomicAdd(&hist[s >> BLOG], 1u);
        srt[is] = rec | ((unsigned)(s & (NPB - 1)) << 23);
        unsigned it = atomicAdd(&hist[d >> BLOG], 1u);
        srt[it] = rec | ((unsigned)(d & (NPB - 1)) << 23);
    }
    __syncthreads();
    // coalesced copy-out of the block's private sorted region
    unsigned int* dstb = buf + (size_t)blk * (size_t)rstride;
    int nrec = 2 * cl;
    for (int i = t; i < nrec; i += 256) dstb[i] = srt[i];
}

// ---------------- phase 2: per-bucket LDS reduction -------------------------
__global__ __launch_bounds__(256) void bucket_kernel(
    const unsigned int* __restrict__ buf,
    const unsigned short* __restrict__ ofs,
    int rstride, int NB, int nbin,
    double* __restrict__ partials)     // 2 doubles per bucket
{
    __shared__ unsigned long long acc[4][NPB];   // replicated per wave
    __shared__ double sha[4], shb[4];
    int b = blockIdx.x;
    int t = threadIdx.x;
    int wid = t >> 6;
    for (int i = t; i < 4 * NPB; i += 256)
        ((unsigned long long*)acc)[i] = 0ull;
    __syncthreads();

    // each thread walks its own contiguous runs (per-lane sequential -> L1 hits)
    for (int run = t; run < nbin; run += 256) {
        size_t row = (size_t)run * (size_t)(NB + 1);
        unsigned o0 = ofs[row + b];
        unsigned o1 = ofs[row + b + 1];
        const unsigned int* p = buf + (size_t)run * (size_t)rstride + o0;
        for (unsigned i = 0; i < o1 - o0; ++i) {
            unsigned r = p[i];
            unsigned id = (r >> 23) & (NPB - 1);
            atomicAdd(&acc[wid][id], rec_to_val(r));
        }
    }
    __syncthreads();

    double pls = 0.0, npr = 0.0;
    for (int i = t; i < NPB; i += 256) {
        unsigned long long a = acc[0][i] + acc[1][i] + acc[2][i] + acc[3][i];
        decode_accum(a, pls, npr);
    }
    for (int off = 32; off > 0; off >>= 1) {
        pls += __shfl_down(pls, off, 64);
        npr += __shfl_down(npr, off, 64);
    }
    int lane = t & 63;
    if (lane == 0) { sha[wid] = pls; shb[wid] = npr; }
    __syncthreads();
    if (t == 0) {
        partials[2 * b + 0] = sha[0] + sha[1] + sha[2] + sha[3];
        partials[2 * b + 1] = shb[0] + shb[1] + shb[2] + shb[3];
    }
}

// ---------------- final: sum partials, divide -------------------------------
__global__ __launch_bounds__(256) void final_kernel(
    const double* __restrict__ partials,
    float* __restrict__ out,
    int nb)
{
    double pls = 0.0, npr = 0.0;
    for (int i = threadIdx.x; i < nb; i += blockDim.x) {
        pls += partials[2 * i + 0];
        npr += partials[2 * i + 1];
    }
    __shared__ double sha[4], shb[4];
    for (int off = 32; off > 0; off >>= 1) {
        pls += __shfl_down(pls, off, 64);
        npr += __shfl_down(npr, off, 64);
    }
    int lane = threadIdx.x & 63;
    int wid = threadIdx.x >> 6;
    if (lane == 0) { sha[wid] = pls; shb[wid] = npr; }
    __syncthreads();
    if (threadIdx.x == 0) {
        double a = sha[0] + sha[1] + sha[2] + sha[3];
        double b = shb[0] + shb[1] + shb[2] + shb[3];
        out[0] = (float)(a / fmax(b, 1.0));
    }
}

// ---------------- fallback path (round-2 proven): device atomics ------------
__global__ __launch_bounds__(256) void edge_kernel_fb(
    const float2* __restrict__ pos,
    const int* __restrict__ ei,
    unsigned long long* __restrict__ acc,
    int E)
{
    int tid = blockIdx.x * blockDim.x + threadIdx.x;
    int nthreads = gridDim.x * blockDim.x;
    const int* src = ei;
    const int* dst = ei + E;
    for (int e = tid; e < E; e += nthreads) {
        int s = src[e], t = dst[e];
        float2 ps = pos[s], pt = pos[t];
        unsigned long long val = rec_to_val(make_record(pt.x - ps.x, pt.y - ps.y));
        atomicAdd(&acc[s], val);
        atomicAdd(&acc[t], val);
    }
}

__global__ __launch_bounds__(256) void node_kernel_fb(
    const unsigned long long* __restrict__ acc,
    double* __restrict__ partials,
    int N)
{
    int tid = blockIdx.x * blockDim.x + threadIdx.x;
    int nthreads = gridDim.x * blockDim.x;
    double pls = 0.0, npr = 0.0;
    for (int n = tid; n < N; n += nthreads)
        decode_accum(acc[n], pls, npr);
    __shared__ double sha[4], shb[4];
    for (int off = 32; off > 0; off >>= 1) {
        pls += __shfl_down(pls, off, 64);
        npr += __shfl_down(npr, off, 64);
    }
    int lane = threadIdx.x & 63;
    int wid = threadIdx.x >> 6;
    if (lane == 0) { sha[wid] = pls; shb[wid] = npr; }
    __syncthreads();
    if (threadIdx.x == 0) {
        partials[2 * blockIdx.x + 0] = sha[0] + sha[1] + sha[2] + sha[3];
        partials[2 * blockIdx.x + 1] = shb[0] + shb[1] + shb[2] + shb[3];
    }
}

extern "C" void kernel_launch(void* const* d_in, const int* in_sizes, int n_in,
                              void* d_out, int out_size, void* d_ws, size_t ws_size,
                              hipStream_t stream) {
    const float* pos = (const float*)d_in[0];   // (1,N,2) interleaved x,y
    const int* ei = (const int*)d_in[2];        // (2,E)
    int N = in_sizes[0] / 2;
    int E = in_sizes[2] / 2;
    float* out = (float*)d_out;

    int NB = (N + NPB - 1) >> BLOG;
    int chunk = (E + NBIN - 1) / NBIN;
    int nrec_max = 2 * chunk;
    int rstride = (nrec_max + 15) & ~15;        // 64 B-aligned regions

    // ws layout: [partials NB*16][buf NBIN*rstride*4][ofs NBIN*(NB+1)*2]
    size_t off_buf = (size_t)NB * 16;
    size_t off_ofs = off_buf + (size_t)NBIN * (size_t)rstride * 4;
    size_t need = off_ofs + (size_t)NBIN * (size_t)(NB + 1) * 2;

    if (ws_size >= need && nrec_max <= SRTN && NB + 1 <= 512 && nrec_max < 65536) {
        double* partials = (double*)d_ws;
        unsigned int* buf = (unsigned int*)((char*)d_ws + off_buf);
        unsigned short* ofs = (unsigned short*)((char*)d_ws + off_ofs);

        bin_kernel<<<NBIN, 256, 0, stream>>>(
            (const float2*)pos, ei, E, NB, chunk, rstride, ofs, buf);
        bucket_kernel<<<NB, 256, 0, stream>>>(buf, ofs, rstride, NB, NBIN, partials);
        final_kernel<<<1, 256, 0, stream>>>(partials, out, NB);
    } else {
        // fallback: device-atomic accumulation (round-2 proven path)
        unsigned long long* acc = (unsigned long long*)d_ws;
        double* partials = (double*)((char*)d_ws + (size_t)N * 8);
        hipMemsetAsync(d_ws, 0, (size_t)N * 8 + (size_t)NODE_BLOCKS * 16, stream);
        int eb = min((E + 255) / 256, 2048);
        edge_kernel_fb<<<eb, 256, 0, stream>>>((const float2*)pos, ei, acc, E);
        node_kernel_fb<<<NODE_BLOCKS, 256, 0, stream>>>(acc, partials, N);
        final_kernel<<<1, 256, 0, stream>>>(partials, out, NODE_BLOCKS);
    }
}